// Round 4
// baseline (821.401 us; speedup 1.0000x reference)
//
#include <hip/hip_runtime.h>

// ---------------------------------------------------------------------------
// (B,T,D)=(4,8192,1024), TREE_DEPTH=10, NUM_NODES=1023. Levels 8..0 do work;
// leaves = mean-8 pooling of x[:, :4096, :] into nodes 511..1022.
//
// R4: ONE persistent kernel (512 blocks) for the entire computation.
// Evidence: R0/R1/R3 all fit "kernel work (~200us) + ~220us fixed/dispatch
// overhead" -> collapse 18 launches into 1. Software grid barrier
// (sense-reversing, agent-scope atomics + threadfence); co-residency
// guaranteed structurally: 512 blocks @ __launch_bounds__(256,2), 49KB LDS.
// No split-K / no fix pass needed anymore (grid size is decoupled from level
// shape inside one kernel): levels 8..4 = 64x64-tile bf16 MFMA with 3-stage
// counted-vmcnt pipeline + swizzled LDS, inline gated epilogue; levels 3..0 =
// fp32 vector dots (preserves absmax behavior). Launches: memset(256B) + 1.
// ---------------------------------------------------------------------------

#define NODES 1023
#define DIM   1024
#define K2    2048
#define NBLK  512
#define NCHUNK 64

typedef short short8 __attribute__((ext_vector_type(8)));
typedef float floatx4 __attribute__((ext_vector_type(4)));

__device__ __forceinline__ unsigned short f2bf(float f) {
    unsigned u = __float_as_uint(f);
    unsigned r = ((u >> 16) & 1u) + 0x7fffu;
    return (unsigned short)((u + r) >> 16);
}

#define GLD16(g, l)                                                            \
    __builtin_amdgcn_global_load_lds(                                          \
        (const __attribute__((address_space(1))) void*)(g),                    \
        (__attribute__((address_space(3))) void*)(l), 16, 0, 0)

// Sense-reversing grid barrier. cnt/gen live in workspace (zeroed by a
// hipMemsetAsync before launch), 128B apart to keep add-line and poll-line
// separate. Relaxed polling (no cache-invalidate storm), acquire semantics
// via the ACQ_REL RMW / trailing threadfence.
__device__ __forceinline__ void gridbar(unsigned* cnt, unsigned* gen) {
    __syncthreads();
    if (threadIdx.x == 0) {
        __threadfence();
        unsigned g = __hip_atomic_load(gen, __ATOMIC_RELAXED,
                                       __HIP_MEMORY_SCOPE_AGENT);
        unsigned a = __hip_atomic_fetch_add(cnt, 1u, __ATOMIC_ACQ_REL,
                                            __HIP_MEMORY_SCOPE_AGENT);
        if (a == (unsigned)(NBLK - 1)) {
            __hip_atomic_store(cnt, 0u, __ATOMIC_RELAXED,
                               __HIP_MEMORY_SCOPE_AGENT);
            __hip_atomic_store(gen, g + 1u, __ATOMIC_RELEASE,
                               __HIP_MEMORY_SCOPE_AGENT);
            __threadfence();
        } else {
            while (__hip_atomic_load(gen, __ATOMIC_RELAXED,
                                     __HIP_MEMORY_SCOPE_AGENT) == g)
                __builtin_amdgcn_s_sleep(1);
            __threadfence();
        }
    }
    __syncthreads();
}

__global__ __launch_bounds__(256, 2) void k_tree(
    const float* __restrict__ W, unsigned short* __restrict__ Wb,
    const float* __restrict__ x, const float* __restrict__ nw,
    const float* __restrict__ bt, const float* __restrict__ rw,
    float* __restrict__ Sf, unsigned short* __restrict__ Sb,
    float* __restrict__ part, float* __restrict__ mixv,
    float* __restrict__ out, unsigned* cnt, unsigned* gen) {
    __shared__ __align__(16) unsigned short Al[3][4096];
    __shared__ __align__(16) unsigned short Bl[3][4096];
    __shared__ float redbuf[256];
    __shared__ float wsum[4];

    const int bid = blockIdx.x;
    const int t = threadIdx.x;
    const int lane = t & 63;
    const int w = t >> 6;

    // ---------------- phase 0: W->bf16 conversion + leaf pooling -----------
    {
        int gtid = bid * 256 + t;
#pragma unroll
        for (int i = 0; i < 4; ++i) {
            int idx = gtid + i * 131072;  // 524288 float4 = 1024x2048 floats
            float4 v = ((const float4*)W)[idx];
            ushort4 o;
            o.x = f2bf(v.x); o.y = f2bf(v.y); o.z = f2bf(v.z); o.w = f2bf(v.w);
            ((ushort4*)Wb)[idx] = o;
        }
#pragma unroll
        for (int j = 0; j < 4; ++j) {
            int u = bid * 4 + j;        // 2048 (leaf, batch) units
            int leaf = u & 511;
            int bb = u >> 9;
            int d = t * 4;
            const float* xp =
                x + ((size_t)bb * 8192 + (size_t)leaf * 8) * DIM + d;
            float4 s = {0.f, 0.f, 0.f, 0.f};
#pragma unroll
            for (int i = 0; i < 8; ++i) {
                float4 v = *(const float4*)(xp + (size_t)i * DIM);
                s.x += v.x; s.y += v.y; s.z += v.z; s.w += v.w;
            }
            s.x *= 0.125f; s.y *= 0.125f; s.z *= 0.125f; s.w *= 0.125f;
            size_t o = ((size_t)bb * NODES + 511 + leaf) * DIM + d;
            *(float4*)(Sf + o) = s;
            ushort4 ob;
            ob.x = f2bf(s.x); ob.y = f2bf(s.y); ob.z = f2bf(s.z); ob.w = f2bf(s.w);
            *(ushort4*)(Sb + o) = ob;
        }
    }
    gridbar(cnt, gen);

    // ---------------- levels 8..0 ------------------------------------------
    for (int L = 8; L >= 0; --L) {
        int R = 4 << L;
        if (L >= 4) {
            // bf16 MFMA path: 64x64 tile, full K (nit=32), 3-stage pipeline.
            int Mt = R >> 6;
            int units = Mt * 16;
            if (bid < units) {
                const int lvl_start = (1 << L) - 1;
                const int child_start = (2 << L) - 1;
                const int mask = (1 << L) - 1;
                const int bm = bid >> 4, bn = bid & 15;
                const int wm = w >> 1, wn = w & 1;

                floatx4 acc[2][2];
#pragma unroll
                for (int i = 0; i < 2; ++i)
#pragma unroll
                    for (int j = 0; j < 2; ++j)
                        acc[i][j] = (floatx4){0.f, 0.f, 0.f, 0.f};

                const int trow = t >> 3;                     // 0..31
                const int csw = ((t & 7) ^ (trow & 7)) * 8;  // swizzled src col

                const unsigned short* aptr[2];
#pragma unroll
                for (int p = 0; p < 2; ++p) {
                    int rg = bm * 64 + p * 32 + trow;
                    int bb = rg >> L;
                    int nl = rg & mask;
                    aptr[p] = Sb + ((size_t)bb * NODES + child_start + 2 * nl) * DIM + csw;
                }
                const unsigned short* bptr[2];
#pragma unroll
                for (int p = 0; p < 2; ++p) {
                    int rg = bn * 64 + p * 32 + trow;
                    bptr[p] = Wb + (size_t)rg * K2 + csw;
                }

#define STAGE(buf, k0)                                                         \
    {                                                                          \
        _Pragma("unroll")                                                      \
        for (int p = 0; p < 2; ++p)                                            \
            GLD16(aptr[p] + (k0), &Al[buf][(p * 32 + w * 8) * 64]);            \
        _Pragma("unroll")                                                      \
        for (int p = 0; p < 2; ++p)                                            \
            GLD16(bptr[p] + (k0), &Bl[buf][(p * 32 + w * 8) * 64]);            \
    }

                const int rsel = lane & 15;
                const int jx = lane >> 4;
                const int swz = lane & 7;

#define COMP(bi)                                                               \
    {                                                                          \
        const char* Ab = (const char*)&Al[bi][0];                              \
        const char* Bb = (const char*)&Bl[bi][0];                              \
        _Pragma("unroll")                                                      \
        for (int ks = 0; ks < 2; ++ks) {                                       \
            short8 af[2], bf[2];                                               \
            _Pragma("unroll")                                                  \
            for (int i = 0; i < 2; ++i) {                                      \
                af[i] = *(const short8*)(Ab + (wm * 32 + i * 16 + rsel) * 128 +\
                                         (((ks * 4 + jx) ^ swz) << 4));        \
                bf[i] = *(const short8*)(Bb + (wn * 32 + i * 16 + rsel) * 128 +\
                                         (((ks * 4 + jx) ^ swz) << 4));        \
            }                                                                  \
            _Pragma("unroll")                                                  \
            for (int i = 0; i < 2; ++i)                                        \
                _Pragma("unroll")                                              \
                for (int j = 0; j < 2; ++j)                                    \
                    acc[i][j] = __builtin_amdgcn_mfma_f32_16x16x32_bf16(       \
                        af[i], bf[j], acc[i][j], 0, 0, 0);                     \
        }                                                                      \
    }

                STAGE(0, 0);
                STAGE(1, 64);
#pragma unroll 3
                for (int it = 0; it < 30; ++it) {
                    asm volatile("s_waitcnt vmcnt(4)" ::: "memory");
                    __builtin_amdgcn_s_barrier();
                    STAGE((it + 2) % 3, (it + 2) * 64);
                    COMP(it % 3);
                }
                asm volatile("s_waitcnt vmcnt(4)" ::: "memory");
                __builtin_amdgcn_s_barrier();
                COMP(0);  // it=30
                asm volatile("s_waitcnt vmcnt(0)" ::: "memory");
                __builtin_amdgcn_s_barrier();
                COMP(1);  // it=31
#undef STAGE
#undef COMP

                // inline epilogue: gate by bt[L], write fp32 + bf16 states
                const float* btL = bt + (size_t)L * DIM;
#pragma unroll
                for (int i = 0; i < 2; ++i)
#pragma unroll
                    for (int j = 0; j < 2; ++j)
#pragma unroll
                        for (int r = 0; r < 4; ++r) {
                            int m = bm * 64 + wm * 32 + i * 16 + (lane >> 4) * 4 + r;
                            int n = bn * 64 + wn * 32 + j * 16 + (lane & 15);
                            float v = acc[i][j][r];
                            float o = (v - btL[n] > 0.f) ? v : 0.f;
                            int bb = m >> L;
                            int nl = m & mask;
                            size_t idx =
                                ((size_t)bb * NODES + lvl_start + nl) * DIM + n;
                            Sf[idx] = o;
                            Sb[idx] = f2bf(o);
                        }
            }
        } else {
            // fp32 vector path (levels 3..0): (r, dtile) units, 4 k-chunks.
            int units = R * 16;
            if (bid < units) {
                int r = bid >> 4, dtile = bid & 15;
                int bb = r >> L;
                int nl = r & ((1 << L) - 1);
                int node = (1 << L) - 1 + nl;
                int child = 2 * node + 1;
                const float* A = Sf + ((size_t)bb * NODES + child) * DIM;

                float* Alds = (float*)&Al[0][0];  // 8KB scratch
                ((float4*)Alds)[t * 2] = ((const float4*)A)[t * 2];
                ((float4*)Alds)[t * 2 + 1] = ((const float4*)A)[t * 2 + 1];
                __syncthreads();

                int d = dtile * 64 + (t & 63);
                int kc = t >> 6;
                const float4* Wr = (const float4*)(W + (size_t)d * K2 + kc * 512);
                const float4* Ar = (const float4*)(Alds + kc * 512);
                float s = 0.f;
#pragma unroll 8
                for (int i = 0; i < 128; ++i) {
                    float4 wv = Wr[i], av = Ar[i];
                    s += wv.x * av.x + wv.y * av.y + wv.z * av.z + wv.w * av.w;
                }
                redbuf[t] = s;
                __syncthreads();
                if (t < 64) {
                    float v = redbuf[t] + redbuf[t + 64] + redbuf[t + 128] +
                              redbuf[t + 192];
                    float u = v - bt[(size_t)L * DIM + d];
                    float o = (u > 0.f) ? v : 0.f;
                    size_t idx = ((size_t)bb * NODES + node) * DIM + d;
                    Sf[idx] = o;  // Sb not needed below L4
                }
            }
        }
        gridbar(cnt, gen);
    }

    // ---------------- mixture phase A: partial sums per 16-node chunk ------
    if (bid < 256) {
        int c = bid >> 2;        // 0..63
        int dblk = bid & 3;
        int d = dblk * 256 + t;  // 0..1023
        int n0i = c * 16;
        int n1i = n0i + 16 < NODES ? n0i + 16 : NODES;
        float denom = 0.f, s0 = 0.f, s1 = 0.f, s2 = 0.f, s3 = 0.f;
        for (int n = n0i; n < n1i; ++n) {
            float wv = __expf(nw[(size_t)n * DIM + d]);
            denom += wv;
            s0 += wv * Sf[((size_t)0 * NODES + n) * DIM + d];
            s1 += wv * Sf[((size_t)1 * NODES + n) * DIM + d];
            s2 += wv * Sf[((size_t)2 * NODES + n) * DIM + d];
            s3 += wv * Sf[((size_t)3 * NODES + n) * DIM + d];
        }
        size_t base = ((size_t)c * 5) * DIM + d;
        part[base]           = denom;
        part[base + 1 * DIM] = s0;
        part[base + 2 * DIM] = s1;
        part[base + 3 * DIM] = s2;
        part[base + 4 * DIM] = s3;
    }
    gridbar(cnt, gen);

    // ---------------- mixture phase B: reduce chunks -----------------------
    if (bid < 4) {
        int d = bid * 256 + t;
        float denom = 0.f, s0 = 0.f, s1 = 0.f, s2 = 0.f, s3 = 0.f;
#pragma unroll 8
        for (int c = 0; c < NCHUNK; ++c) {
            size_t base = ((size_t)c * 5) * DIM + d;
            denom += part[base];
            s0 += part[base + 1 * DIM];
            s1 += part[base + 2 * DIM];
            s2 += part[base + 3 * DIM];
            s3 += part[base + 4 * DIM];
        }
        float inv = 1.f / denom;
        mixv[0 * DIM + d] = s0 * inv;
        mixv[1 * DIM + d] = s1 * inv;
        mixv[2 * DIM + d] = s2 * inv;
        mixv[3 * DIM + d] = s3 * inv;
    }
    gridbar(cnt, gen);

    // ---------------- final: out = rmsnorm(x + mixture) * rms_w ------------
    {
        float4 rwv = *(const float4*)(rw + t * 4);
        for (int row = bid; row < 32768; row += NBLK) {
            int bb = row >> 13;
            size_t base = (size_t)row * DIM;
            float4 xv = *(const float4*)(x + base + t * 4);
            float4 mv = *(const float4*)(mixv + (size_t)bb * DIM + t * 4);
            float4 v = {xv.x + mv.x, xv.y + mv.y, xv.z + mv.z, xv.w + mv.w};
            float ss = v.x * v.x + v.y * v.y + v.z * v.z + v.w * v.w;
#pragma unroll
            for (int o = 32; o > 0; o >>= 1) ss += __shfl_xor(ss, o, 64);
            if (lane == 0) wsum[w] = ss;
            __syncthreads();
            float tot = wsum[0] + wsum[1] + wsum[2] + wsum[3];
            float inv = 1.f / sqrtf(tot * (1.f / 1024.f) + 1.1920929e-7f);
            float4 o4 = {v.x * inv * rwv.x, v.y * inv * rwv.y,
                         v.z * inv * rwv.z, v.w * inv * rwv.w};
            *(float4*)(out + base + t * 4) = o4;
            __syncthreads();  // protect wsum before next row
        }
    }
}

// ----------------------------------------------------------------------------
extern "C" void kernel_launch(void* const* d_in, const int* in_sizes, int n_in,
                              void* d_out, int out_size, void* d_ws, size_t ws_size,
                              hipStream_t stream) {
    (void)in_sizes; (void)n_in; (void)out_size; (void)ws_size;
    const float* x  = (const float*)d_in[0];
    const float* W  = (const float*)d_in[1];
    const float* nw = (const float*)d_in[2];
    const float* bt = (const float*)d_in[3];
    // d_in[4] = as_w, multiplied by 0.0 in reference -> unused
    const float* rw = (const float*)d_in[5];
    float* out = (float*)d_out;

    char* ws = (char*)d_ws;
    const size_t SF_BYTES = (size_t)4 * NODES * DIM * 4;   // 16,760,832
    const size_t SB_BYTES = (size_t)4 * NODES * DIM * 2;   //  8,380,416
    const size_t WB_BYTES = (size_t)K2 * DIM * 2;          //  4,194,304
    const size_t MIX_BYTES = (size_t)4 * DIM * 4;          //     16,384
    const size_t BASE = SF_BYTES + SB_BYTES + WB_BYTES + MIX_BYTES;
    float* Sf = (float*)ws;
    unsigned short* Sb = (unsigned short*)(ws + SF_BYTES);
    unsigned short* Wb = (unsigned short*)(ws + SF_BYTES + SB_BYTES);
    float* mixv = (float*)(ws + SF_BYTES + SB_BYTES + WB_BYTES);
    float* part = (float*)(ws + BASE);                     // 1.31 MB
    unsigned* bar = (unsigned*)(ws + BASE + 2 * 1024 * 1024);

    hipMemsetAsync(bar, 0, 256, stream);
    k_tree<<<NBLK, 256, 0, stream>>>(W, Wb, x, nw, bt, rw, Sf, Sb, part, mixv,
                                     out, bar, bar + 32);
}

// Round 6
// 412.698 us; speedup vs baseline: 1.9903x; 1.9903x over previous
//
#include <hip/hip_runtime.h>

// ---------------------------------------------------------------------------
// (B,T,D)=(4,8192,1024), TREE_DEPTH=10, NUM_NODES=1023. Levels 8..0 do work;
// leaves = mean-8 pooling of x[:, :4096, :] into nodes 511..1022.
//
// R6 = resubmit of R5 (round-5 bench died in the harness's async framework:
// "ExceptionGroup: Exceptions from Trio nursery" — third infra failure this
// session; R0/R2 showed the same class of error against kernels that later
// ran fine). Kernel re-audited statically: bounds, barrier schedule, Sb
// producer/consumer chain, workspace all check out.
//
// R5 design (vs 420.8us R3): minimize launch COUNT (18 -> 13), no sync-
// structure risk. R4's persistent-kernel experiment proved fusion-with-grid-
// barriers regresses (per-block threadfence = L2 wb/inv storm, 6% HBM util);
// R3 data implies ~13us per launch.
//  * no split-K, no fix kernels: per-level wall time is pipeline-bound
//    (~4-5us) regardless of grid size; fix launches cost more than they save.
//    Levels L8..L4 run at 256/128/64/32/16 blocks, inline gated epilogue.
//  * k_prep fuses W->bf16 + leaf pooling (1 launch, 4096 blocks).
//  * k_level_small: one WAVE per output row -> W reads coalesced (1KB
//    contiguous per wave) instead of 64 lanes at 8KB stride.
//  * dead writes dropped (Sb at L4; P buffer gone).
// Launches: prep, 5 MFMA levels, 4 small levels, mixA, mixB, final = 13.
// ---------------------------------------------------------------------------

#define NODES 1023
#define DIM   1024
#define K2    2048
#define NCHUNK 64

typedef short short8 __attribute__((ext_vector_type(8)));
typedef float floatx4 __attribute__((ext_vector_type(4)));

__device__ __forceinline__ unsigned short f2bf(float f) {
    unsigned u = __float_as_uint(f);
    unsigned r = ((u >> 16) & 1u) + 0x7fffu;
    return (unsigned short)((u + r) >> 16);
}

#define GLD16(g, l)                                                            \
    __builtin_amdgcn_global_load_lds(                                          \
        (const __attribute__((address_space(1))) void*)(g),                    \
        (__attribute__((address_space(3))) void*)(l), 16, 0, 0)

// ------------------- fused W->bf16 convert + leaf pooling -------------------
// grid = 2048 (cvt) + 2048 (leaves: leaf 0..511 x b 0..3)
__global__ __launch_bounds__(256) void k_prep(const float* __restrict__ W,
                                              unsigned short* __restrict__ Wb,
                                              const float* __restrict__ x,
                                              float* __restrict__ Sf,
                                              unsigned short* __restrict__ Sb) {
    int bx = blockIdx.x;
    if (bx < 2048) {
        int i = (bx * 256 + threadIdx.x) * 4;
        float4 v = *(const float4*)(W + i);
        ushort4 o;
        o.x = f2bf(v.x); o.y = f2bf(v.y); o.z = f2bf(v.z); o.w = f2bf(v.w);
        *(ushort4*)(Wb + i) = o;
    } else {
        int idx = bx - 2048;
        int leaf = idx & 511;
        int b = idx >> 9;
        int d = threadIdx.x * 4;
        const float* xp = x + ((size_t)b * 8192 + (size_t)leaf * 8) * DIM + d;
        float4 s = {0.f, 0.f, 0.f, 0.f};
#pragma unroll
        for (int i = 0; i < 8; ++i) {
            float4 v = *(const float4*)(xp + (size_t)i * DIM);
            s.x += v.x; s.y += v.y; s.z += v.z; s.w += v.w;
        }
        s.x *= 0.125f; s.y *= 0.125f; s.z *= 0.125f; s.w *= 0.125f;
        size_t o = ((size_t)b * NODES + 511 + leaf) * DIM + d;
        *(float4*)(Sf + o) = s;
        ushort4 ob;
        ob.x = f2bf(s.x); ob.y = f2bf(s.y); ob.z = f2bf(s.z); ob.w = f2bf(s.w);
        *(ushort4*)(Sb + o) = ob;
    }
}

// --------------------------- MFMA level (L >= 4) -----------------------------
// GEMM: R = 4<<L rows, K=2048, N=1024. A row r: b=r>>L, n=r&(2^L-1),
// base = Sb[b][child_start + 2n][0..2047] (contiguous). B = Wb (1024x2048 NT).
// 64x64 tile, 4 waves of 32x32 (2x2 frags of 16x16x32 bf16), full K (32 iters),
// 3-stage LDS pipeline with counted vmcnt(4), swizzled staging (rule #21:
// linear LDS dest, pre-swizzled global source col, same XOR on ds_read).
// grid = dim3(16, R/64).
__global__ __launch_bounds__(256) void k_level_mfma(
    const unsigned short* __restrict__ SbIn, const unsigned short* __restrict__ Wb,
    const float* __restrict__ bt, float* __restrict__ Sf,
    unsigned short* __restrict__ SbOut, int L) {
    const int lvl_start = (1 << L) - 1;
    const int child_start = (2 << L) - 1;
    const int mask = (1 << L) - 1;

    __shared__ __align__(16) unsigned short Al[3][4096];
    __shared__ __align__(16) unsigned short Bl[3][4096];

    const int t = threadIdx.x;
    const int lane = t & 63;
    const int w = t >> 6;
    const int wm = w >> 1, wn = w & 1;
    const int bm = blockIdx.y, bn = blockIdx.x;

    floatx4 acc[2][2];
#pragma unroll
    for (int i = 0; i < 2; ++i)
#pragma unroll
        for (int j = 0; j < 2; ++j) acc[i][j] = (floatx4){0.f, 0.f, 0.f, 0.f};

    const int trow = t >> 3;                     // 0..31 (row within 32-row stage)
    const int csw = ((t & 7) ^ (trow & 7)) * 8;  // swizzled source col (shorts)

    const unsigned short* aptr[2];
#pragma unroll
    for (int p = 0; p < 2; ++p) {
        int rg = bm * 64 + p * 32 + trow;
        int bb = rg >> L;
        int nl = rg & mask;
        aptr[p] = SbIn + ((size_t)bb * NODES + child_start + 2 * nl) * DIM + csw;
    }
    const unsigned short* bptr[2];
#pragma unroll
    for (int p = 0; p < 2; ++p) {
        int rg = bn * 64 + p * 32 + trow;
        bptr[p] = Wb + (size_t)rg * K2 + csw;
    }

#define STAGE(buf, k0)                                                         \
    {                                                                          \
        _Pragma("unroll")                                                      \
        for (int p = 0; p < 2; ++p)                                            \
            GLD16(aptr[p] + (k0), &Al[buf][(p * 32 + w * 8) * 64]);            \
        _Pragma("unroll")                                                      \
        for (int p = 0; p < 2; ++p)                                            \
            GLD16(bptr[p] + (k0), &Bl[buf][(p * 32 + w * 8) * 64]);            \
    }

    const int rsel = lane & 15;
    const int jx = lane >> 4;
    const int swz = lane & 7;

#define COMP(bi)                                                               \
    {                                                                          \
        const char* Ab = (const char*)&Al[bi][0];                              \
        const char* Bb = (const char*)&Bl[bi][0];                              \
        _Pragma("unroll")                                                      \
        for (int ks = 0; ks < 2; ++ks) {                                       \
            short8 af[2], bf[2];                                               \
            _Pragma("unroll")                                                  \
            for (int i = 0; i < 2; ++i) {                                      \
                af[i] = *(const short8*)(Ab + (wm * 32 + i * 16 + rsel) * 128 +\
                                         (((ks * 4 + jx) ^ swz) << 4));        \
                bf[i] = *(const short8*)(Bb + (wn * 32 + i * 16 + rsel) * 128 +\
                                         (((ks * 4 + jx) ^ swz) << 4));        \
            }                                                                  \
            _Pragma("unroll")                                                  \
            for (int i = 0; i < 2; ++i)                                        \
                _Pragma("unroll")                                              \
                for (int j = 0; j < 2; ++j)                                    \
                    acc[i][j] = __builtin_amdgcn_mfma_f32_16x16x32_bf16(       \
                        af[i], bf[j], acc[i][j], 0, 0, 0);                     \
        }                                                                      \
    }

    STAGE(0, 0);
    STAGE(1, 64);
#pragma unroll 3
    for (int it = 0; it < 30; ++it) {
        asm volatile("s_waitcnt vmcnt(4)" ::: "memory");
        __builtin_amdgcn_s_barrier();
        STAGE((it + 2) % 3, (it + 2) * 64);
        COMP(it % 3);
    }
    asm volatile("s_waitcnt vmcnt(4)" ::: "memory");
    __builtin_amdgcn_s_barrier();
    COMP(0);  // K-tile 30
    asm volatile("s_waitcnt vmcnt(0)" ::: "memory");
    __builtin_amdgcn_s_barrier();
    COMP(1);  // K-tile 31
#undef STAGE
#undef COMP

    // inline epilogue: gate by bt[L]; Sf always (mixA reads it); Sb only if a
    // later MFMA level consumes it (L>4).
    const float* btL = bt + (size_t)L * DIM;
#pragma unroll
    for (int i = 0; i < 2; ++i)
#pragma unroll
        for (int j = 0; j < 2; ++j)
#pragma unroll
            for (int r = 0; r < 4; ++r) {
                int m = bm * 64 + wm * 32 + i * 16 + (lane >> 4) * 4 + r;
                int n = bn * 64 + wn * 32 + j * 16 + (lane & 15);
                float v = acc[i][j][r];
                float o = (v - btL[n] > 0.f) ? v : 0.f;
                int bb = m >> L;
                int nl = m & mask;
                size_t idx = ((size_t)bb * NODES + lvl_start + nl) * DIM + n;
                Sf[idx] = o;
                if (L > 4) SbOut[idx] = f2bf(o);
            }
}

// ------------------------- small level (L <= 3), fp32 ------------------------
// grid = (16 dtiles, R rows). One WAVE computes one output row d at a time:
// lanes split K (coalesced 1KB W segments), butterfly-reduce, lane0 writes.
__global__ __launch_bounds__(256) void k_level_small(
    const float* __restrict__ SfIn, const float* __restrict__ W,
    const float* __restrict__ bt, float* __restrict__ Sf, int L) {
    int r = blockIdx.y;
    int b = r >> L;
    int nl = r & ((1 << L) - 1);
    int node = (1 << L) - 1 + nl;
    int child = 2 * node + 1;
    const float* A = SfIn + ((size_t)b * NODES + child) * DIM;  // 2048 floats

    __shared__ float Alds[K2];
    int t = threadIdx.x;
    ((float4*)Alds)[t * 2] = ((const float4*)A)[t * 2];
    ((float4*)Alds)[t * 2 + 1] = ((const float4*)A)[t * 2 + 1];
    __syncthreads();

    int lane = t & 63;
    int wv = t >> 6;
#pragma unroll 4
    for (int q = 0; q < 16; ++q) {
        int dd = blockIdx.x * 64 + wv * 16 + q;
        const float4* Wr = (const float4*)(W + (size_t)dd * K2);
        const float4* Ar = (const float4*)Alds;
        float s = 0.f;
#pragma unroll
        for (int j = 0; j < 8; ++j) {
            float4 wv4 = Wr[j * 64 + lane];
            float4 av = Ar[j * 64 + lane];
            s += wv4.x * av.x + wv4.y * av.y + wv4.z * av.z + wv4.w * av.w;
        }
#pragma unroll
        for (int o = 32; o > 0; o >>= 1) s += __shfl_xor(s, o, 64);
        if (lane == 0) {
            float u = s - bt[(size_t)L * DIM + dd];
            float o = (u > 0.f) ? s : 0.f;
            Sf[((size_t)b * NODES + node) * DIM + dd] = o;
        }
    }
}

// ---------------- softmax mixture, phase A: partial sums per chunk -----------
__global__ __launch_bounds__(256) void k_mixture_part(const float* __restrict__ nw,
                                                      const float* __restrict__ Sf,
                                                      float* __restrict__ part) {
    int d = blockIdx.x * 256 + threadIdx.x;  // 0..1023
    int c = blockIdx.y;
    int n0i = c * 16;
    int n1i = n0i + 16 < NODES ? n0i + 16 : NODES;
    float denom = 0.f, s0 = 0.f, s1 = 0.f, s2 = 0.f, s3 = 0.f;
    for (int n = n0i; n < n1i; ++n) {
        float wv = __expf(nw[(size_t)n * DIM + d]);
        denom += wv;
        s0 += wv * Sf[((size_t)0 * NODES + n) * DIM + d];
        s1 += wv * Sf[((size_t)1 * NODES + n) * DIM + d];
        s2 += wv * Sf[((size_t)2 * NODES + n) * DIM + d];
        s3 += wv * Sf[((size_t)3 * NODES + n) * DIM + d];
    }
    size_t base = ((size_t)c * 5) * DIM + d;
    part[base]           = denom;
    part[base + 1 * DIM] = s0;
    part[base + 2 * DIM] = s1;
    part[base + 3 * DIM] = s2;
    part[base + 4 * DIM] = s3;
}

// ---------------- softmax mixture, phase B: reduce chunks --------------------
__global__ __launch_bounds__(256) void k_mixture_red(const float* __restrict__ part,
                                                     float* __restrict__ mix) {
    int d = blockIdx.x * 256 + threadIdx.x;  // 0..1023
    float denom = 0.f, s0 = 0.f, s1 = 0.f, s2 = 0.f, s3 = 0.f;
#pragma unroll 8
    for (int c = 0; c < NCHUNK; ++c) {
        size_t base = ((size_t)c * 5) * DIM + d;
        denom += part[base];
        s0 += part[base + 1 * DIM];
        s1 += part[base + 2 * DIM];
        s2 += part[base + 3 * DIM];
        s3 += part[base + 4 * DIM];
    }
    float inv = 1.f / denom;
    mix[0 * DIM + d] = s0 * inv;
    mix[1 * DIM + d] = s1 * inv;
    mix[2 * DIM + d] = s2 * inv;
    mix[3 * DIM + d] = s3 * inv;
}

// --------------------- out = rmsnorm(x + mixture) * rms_w --------------------
__global__ __launch_bounds__(256) void k_final(const float* __restrict__ x,
                                               const float* __restrict__ mix,
                                               const float* __restrict__ rw,
                                               float* __restrict__ out) {
    int row = blockIdx.x;       // b*8192 + t
    int b = row >> 13;
    size_t base = (size_t)row * DIM;
    int t = threadIdx.x;
    float4 xv = *(const float4*)(x + base + t * 4);
    float4 mv = *(const float4*)(mix + b * DIM + t * 4);
    float4 v = {xv.x + mv.x, xv.y + mv.y, xv.z + mv.z, xv.w + mv.w};
    float ss = v.x * v.x + v.y * v.y + v.z * v.z + v.w * v.w;
#pragma unroll
    for (int o = 32; o > 0; o >>= 1) ss += __shfl_xor(ss, o, 64);
    __shared__ float wsum[4];
    int lane = t & 63, wv_ = t >> 6;
    if (lane == 0) wsum[wv_] = ss;
    __syncthreads();
    float tot = wsum[0] + wsum[1] + wsum[2] + wsum[3];
    float inv = 1.f / sqrtf(tot * (1.f / 1024.f) + 1.1920929e-7f);
    float4 rwv = *(const float4*)(rw + t * 4);
    float4 o4 = {v.x * inv * rwv.x, v.y * inv * rwv.y, v.z * inv * rwv.z,
                 v.w * inv * rwv.w};
    *(float4*)(out + base + t * 4) = o4;
}

// ----------------------------------------------------------------------------
extern "C" void kernel_launch(void* const* d_in, const int* in_sizes, int n_in,
                              void* d_out, int out_size, void* d_ws, size_t ws_size,
                              hipStream_t stream) {
    (void)in_sizes; (void)n_in; (void)out_size; (void)ws_size;
    const float* x  = (const float*)d_in[0];
    const float* W  = (const float*)d_in[1];
    const float* nw = (const float*)d_in[2];
    const float* bt = (const float*)d_in[3];
    // d_in[4] = as_w, multiplied by 0.0 in reference -> unused
    const float* rw = (const float*)d_in[5];
    float* out = (float*)d_out;

    char* ws = (char*)d_ws;
    const size_t SF_BYTES = (size_t)4 * NODES * DIM * 4;   // 16,760,832
    const size_t SB_BYTES = (size_t)4 * NODES * DIM * 2;   //  8,380,416
    const size_t WB_BYTES = (size_t)K2 * DIM * 2;          //  4,194,304
    const size_t MIX_BYTES = (size_t)4 * DIM * 4;          //     16,384
    const size_t BASE = SF_BYTES + SB_BYTES + WB_BYTES + MIX_BYTES;
    float* Sf = (float*)ws;
    unsigned short* Sb = (unsigned short*)(ws + SF_BYTES);
    unsigned short* Wb = (unsigned short*)(ws + SF_BYTES + SB_BYTES);
    float* mix = (float*)(ws + SF_BYTES + SB_BYTES + WB_BYTES);
    float* part = (float*)(ws + BASE);                     // 1.31 MB

    k_prep<<<4096, 256, 0, stream>>>(W, Wb, x, Sf, Sb);

    for (int L = 8; L >= 4; --L) {
        int Mt = (4 << L) >> 6;   // R/64: 16,8,4,2,1
        k_level_mfma<<<dim3(16, Mt), 256, 0, stream>>>(Sb, Wb, bt, Sf, Sb, L);
    }
    for (int L = 3; L >= 0; --L) {
        int R = 4 << L;
        k_level_small<<<dim3(16, R), 256, 0, stream>>>(Sf, W, bt, Sf, L);
    }
    k_mixture_part<<<dim3(4, NCHUNK), 256, 0, stream>>>(nw, Sf, part);
    k_mixture_red<<<4, 256, 0, stream>>>(part, mix);
    k_final<<<32768, 256, 0, stream>>>(x, mix, rw, out);
}